// Round 4
// baseline (97.335 us; speedup 1.0000x reference)
//
#include <hip/hip_runtime.h>

constexpr int B = 8;
constexpr int A = 49104;
constexpr int C = 90;
constexpr int M = 32;
constexpr float EPS_CLIP = 1e-4f;
constexpr float LN2 = 0.6931471805599453f;

constexpr int TPB = 256;
constexpr int UNB = 8;                                  // load batch depth
constexpr int N4_IMG = A * C / 4;                       // 1,104,840 float4 per image
constexpr int CHUNK = TPB * UNB;                        // 2048 float4 per block-iter
constexpr int NCHUNK = (N4_IMG + CHUNK - 1) / CHUNK;    // 540
constexpr int GRIDX_B = 256;                            // 2048 blocks total

// accum (d_ws): [0..B) S (sum p^2*log2(1-p), all elems), [B..2B) corr (natural domain),
//               [2B..3B) reg_sum, [3B..4B) pos_cnt

__device__ __forceinline__ float clampp(float v) {
    return fminf(fmaxf(v, EPS_CLIP), 1.f - EPS_CLIP);   // -> v_med3_f32
}

// ---------------- Kernel A: per-anchor assignment, reg loss, corrections ----------------
__global__ __launch_bounds__(TPB) void focal_anchor_kernel(
    const float* __restrict__ cls,   // [B, A, C]
    const float* __restrict__ reg,   // [B, A, 4]
    const float* __restrict__ anc,   // [A, 4]
    const float* __restrict__ ann,   // [B, M, 5]
    float* __restrict__ accum)
{
    __shared__ float s_ann[M * 5];
    __shared__ float s_red[3][TPB / 64];

    const int b = blockIdx.y;
    const int abase = blockIdx.x * TPB;
    const int t = threadIdx.x;

    if (t < M * 5) s_ann[t] = ann[b * M * 5 + t];
    __syncthreads();

    float corr = 0.f, reg_sum = 0.f, pos_cnt = 0.f;
    const int a = abase + t;
    if (a < A) {
        const float4 ab = reinterpret_cast<const float4*>(anc)[a];
        const float aw = ab.z - ab.x;
        const float ah = ab.w - ab.y;
        const float areaA = aw * ah;

        float best = -INFINITY;
        int argm = 0;
        for (int m = 0; m < M; ++m) {
            const float bx1 = s_ann[m * 5 + 0];
            const float by1 = s_ann[m * 5 + 1];
            const float bx2 = s_ann[m * 5 + 2];
            const float by2 = s_ann[m * 5 + 3];
            const float lab = s_ann[m * 5 + 4];
            float iw = fminf(ab.z, bx2) - fmaxf(ab.x, bx1);
            float ih = fminf(ab.w, by2) - fmaxf(ab.y, by1);
            iw = fmaxf(iw, 0.f);
            ih = fmaxf(ih, 0.f);
            const float inter = iw * ih;
            const float ua = fmaxf(areaA + (bx2 - bx1) * (by2 - by1) - inter, 1e-8f);
            const float iou = inter / ua;
            const float val = (lab != -1.0f) ? iou : -1.0f;
            if (val > best) { best = val; argm = m; }    // strict > == first argmax
        }

        if (best >= 0.5f) {
            // ---- positive anchor ----
            pos_cnt = 1.f;
            const float gx1 = s_ann[argm * 5 + 0];
            const float gy1 = s_ann[argm * 5 + 1];
            const float gx2 = s_ann[argm * 5 + 2];
            const float gy2 = s_ann[argm * 5 + 3];
            const float acx = ab.x + 0.5f * aw;
            const float acy = ab.y + 0.5f * ah;
            const float gw0 = gx2 - gx1;
            const float gh0 = gy2 - gy1;
            const float gcx = gx1 + 0.5f * gw0;
            const float gcy = gy1 + 0.5f * gh0;
            const float gw = fmaxf(gw0, 1.f);
            const float gh = fmaxf(gh0, 1.f);
            const float4 rp = reinterpret_cast<const float4*>(reg)[(size_t)b * A + a];
            const float rt0 = (gcx - acx) / aw * 10.f;
            const float rt1 = (gcy - acy) / ah * 10.f;
            const float rt2 = __logf(gw / aw) * 5.f;
            const float rt3 = __logf(gh / ah) * 5.f;
            const float d0 = fabsf(rt0 - rp.x);
            const float d1 = fabsf(rt1 - rp.y);
            const float d2 = fabsf(rt2 - rp.z);
            const float d3 = fabsf(rt3 - rp.w);
            auto sl1 = [](float d) {
                return (d <= (1.f / 9.f)) ? 4.5f * d * d : d - (0.5f / 9.f);
            };
            reg_sum = sl1(d0) + sl1(d1) + sl1(d2) + sl1(d3);

            // correction at the target class: remove neg term, add pos term
            const int cidx = (int)s_ann[argm * 5 + 4];
            const float p = clampp(cls[((size_t)b * A + a) * C + cidx]);
            corr = 0.75f * LN2 * (p * p * __log2f(1.f - p))      // cancels streamed neg term
                 + 0.25f * (1.f - p) * (1.f - p) * (-__logf(p)); // true positive term
        } else if (best >= 0.4f) {
            // ---- ignore anchor: cancel all 90 streamed neg terms ----
            const float* row = cls + ((size_t)b * A + a) * C;
            float s = 0.f;
            for (int c = 0; c < C; ++c) {
                const float p = clampp(row[c]);
                s = fmaf(p * p, __log2f(1.f - p), s);
            }
            corr = 0.75f * LN2 * s;
        }
    }

    // block reduce {corr, reg_sum, pos_cnt}
    float v0 = corr, v1 = reg_sum, v2 = pos_cnt;
    for (int off = 32; off; off >>= 1) {
        v0 += __shfl_down(v0, off);
        v1 += __shfl_down(v1, off);
        v2 += __shfl_down(v2, off);
    }
    const int wave = t >> 6;
    if ((t & 63) == 0) { s_red[0][wave] = v0; s_red[1][wave] = v1; s_red[2][wave] = v2; }
    __syncthreads();
    if (t == 0) {
        float a0 = 0.f, a1 = 0.f, a2 = 0.f;
        for (int w = 0; w < TPB / 64; ++w) { a0 += s_red[0][w]; a1 += s_red[1][w]; a2 += s_red[2][w]; }
        atomicAdd(&accum[B + b],     a0);
        atomicAdd(&accum[2 * B + b], a1);
        atomicAdd(&accum[3 * B + b], a2);
    }
}

// ---------------- Kernel B: uniform pure-negative streaming reduction ----------------
__global__ __launch_bounds__(TPB) void focal_neg_stream_kernel(
    const float* __restrict__ cls,   // [B, A, C]
    float* __restrict__ accum)
{
    __shared__ float s_red[TPB / 64];
    const int b = blockIdx.y;
    const int t = threadIdx.x;
    const float4* __restrict__ cp = reinterpret_cast<const float4*>(cls) + (size_t)b * N4_IMG;

    float acc = 0.f;
    for (int c = blockIdx.x; c < NCHUNK; c += GRIDX_B) {
        const int base = c * CHUNK + t;
        if ((c + 1) * CHUNK <= N4_IMG) {
            // full chunk: 8 independent loads, then uniform math
            float4 v[UNB];
#pragma unroll
            for (int k = 0; k < UNB; ++k) v[k] = cp[base + k * TPB];
#pragma unroll
            for (int k = 0; k < UNB; ++k) {
                const float vv[4] = {v[k].x, v[k].y, v[k].z, v[k].w};
#pragma unroll
                for (int j = 0; j < 4; ++j) {
                    const float p = clampp(vv[j]);
                    acc = fmaf(p * p, __log2f(1.f - p), acc);
                }
            }
        } else {
            float4 v[UNB];
#pragma unroll
            for (int k = 0; k < UNB; ++k) {
                const int ix = base + k * TPB;
                v[k] = cp[ix < N4_IMG ? ix : 0];
            }
#pragma unroll
            for (int k = 0; k < UNB; ++k) {
                if (base + k * TPB < N4_IMG) {
                    const float vv[4] = {v[k].x, v[k].y, v[k].z, v[k].w};
#pragma unroll
                    for (int j = 0; j < 4; ++j) {
                        const float p = clampp(vv[j]);
                        acc = fmaf(p * p, __log2f(1.f - p), acc);
                    }
                }
            }
        }
    }

    for (int off = 32; off; off >>= 1) acc += __shfl_down(acc, off);
    if ((t & 63) == 0) s_red[t >> 6] = acc;
    __syncthreads();
    if (t == 0) {
        float a0 = 0.f;
        for (int w = 0; w < TPB / 64; ++w) a0 += s_red[w];
        atomicAdd(&accum[b], a0);
    }
}

// ---------------- Finalize ----------------
__global__ void focal_finalize_kernel(const float* __restrict__ ann,
                                      const float* __restrict__ accum,
                                      float* __restrict__ out)
{
    const int t = threadIdx.x;
    float cls_l = 0.f, reg_l = 0.f;
    if (t < B) {
        bool has = false;
        for (int m = 0; m < M; ++m)
            has = has || (ann[t * M * 5 + m * 5 + 4] != -1.0f);
        const float S    = accum[t];
        const float corr = accum[B + t];
        const float rs   = accum[2 * B + t];
        const float np   = accum[3 * B + t];
        const float cls_sum = -0.75f * LN2 * S + corr;
        cls_l = has ? cls_sum / fmaxf(np, 1.f) : 0.f;
        reg_l = (has && np > 0.f) ? rs / fmaxf(np * 4.f, 1.f) : 0.f;
    }
    for (int off = 4; off; off >>= 1) {
        cls_l += __shfl_down(cls_l, off);
        reg_l += __shfl_down(reg_l, off);
    }
    if (t == 0) {
        out[0] = cls_l * (1.f / B);
        out[1] = reg_l * (1.f / B);
    }
}

extern "C" void kernel_launch(void* const* d_in, const int* in_sizes, int n_in,
                              void* d_out, int out_size, void* d_ws, size_t ws_size,
                              hipStream_t stream) {
    const float* cls = (const float*)d_in[0];
    const float* reg = (const float*)d_in[1];
    const float* anc = (const float*)d_in[2];
    const float* ann = (const float*)d_in[3];
    float* out = (float*)d_out;
    float* accum = (float*)d_ws;

    hipMemsetAsync(accum, 0, 4 * B * sizeof(float), stream);

    dim3 gridA((A + TPB - 1) / TPB, B);
    focal_anchor_kernel<<<gridA, TPB, 0, stream>>>(cls, reg, anc, ann, accum);

    dim3 gridB(GRIDX_B, B);
    focal_neg_stream_kernel<<<gridB, TPB, 0, stream>>>(cls, accum);

    focal_finalize_kernel<<<1, 64, 0, stream>>>(ann, accum, out);
}